// Round 1
// baseline (1824.947 us; speedup 1.0000x reference)
//
#include <hip/hip_runtime.h>

#define NN 50000
#define EE 800000
#define IND 128
#define NCOL 1024
#define KM 320            // K * Mpad = 10*32
#define M30 30
#define RATIO 0.1825741858f   // 30^-0.5
#define EPSF 1e-6f
#define QKSCALE 0.7071067812f // (1/sqrt(0.25)) * 64^-0.25

__device__ __forceinline__ unsigned f2s(float f) {
    unsigned u = __float_as_uint(f);
    return (u & 0x80000000u) ? ~u : (u | 0x80000000u);
}
__device__ __forceinline__ float s2f(unsigned s) {
    return __uint_as_float((s & 0x80000000u) ? (s & 0x7fffffffu) : ~s);
}

// ---------- prep: Wt[IND][NCOL] (cols: 0-255 s*Wq^T, 256-511 s*Wk^T, 512-767 Wv^T,
// 768-895 Pq[h,m], 896-1023 Pk[h,m]), bias_ext[NCOL], WoT[256][64]
__global__ void k_prep(const float* __restrict__ Wq, const float* __restrict__ Wqb,
                       const float* __restrict__ Wk, const float* __restrict__ Wkb,
                       const float* __restrict__ Wv, const float* __restrict__ Wvb,
                       const float* __restrict__ Wo, const float* __restrict__ proj,
                       float* __restrict__ Wt, float* __restrict__ bext, float* __restrict__ WoT) {
    int i = blockIdx.x;   // 0..127
    int t = threadIdx.x;  // 0..255
    Wt[i*NCOL + t]       = QKSCALE * Wq[t*IND + i];
    Wt[i*NCOL + 256 + t] = QKSCALE * Wk[t*IND + i];
    Wt[i*NCOL + 512 + t] = Wv[t*IND + i];
    {
        const float* W = (t < 128) ? Wq : Wk;
        int c = (t < 128) ? t : (t - 128);
        int h = c >> 5, m = c & 31;
        float val = 0.f;
        if (m < M30) {
            for (int d = 0; d < 64; ++d)
                val += QKSCALE * W[(h*64+d)*IND + i] * proj[m*64 + d];
        }
        Wt[i*NCOL + 768 + t] = val;
    }
    if (t < 128) {
        int f = i*2 + (t >> 6);
        int o = t & 63;
        WoT[f*64 + o] = Wo[o*256 + f];
    }
    if (i == 0) {
        bext[t]       = QKSCALE * Wqb[t];
        bext[256 + t] = QKSCALE * Wkb[t];
        bext[512 + t] = Wvb[t];
        const float* Bb = (t < 128) ? Wqb : Wkb;
        int c = (t < 128) ? t : (t - 128);
        int h = c >> 5, m = c & 31;
        float val = 0.f;
        if (m < M30) {
            for (int d = 0; d < 64; ++d)
                val += QKSCALE * Bb[h*64+d] * proj[m*64 + d];
        }
        bext[768 + t] = val;
    }
}

// ---------- fused QKV + dash GEMM + feature maps. 16 nodes per block.
__global__ __launch_bounds__(256) void k_qkv(const float* __restrict__ z, const float* __restrict__ Wt,
                      const float* __restrict__ bext,
                      float* __restrict__ vbuf, float* __restrict__ qp, float* __restrict__ kpb,
                      unsigned* __restrict__ stab) {
    __shared__ float zl[IND][16];
    __shared__ float diag[16][2][4];
    int t = threadIdx.x;
    int n0 = blockIdx.x * 16;
    #pragma unroll
    for (int ss = 0; ss < 2; ++ss) {
        int s = t + ss*256;
        int node = s >> 5;
        int ii = (s & 31) * 4;
        float4 zv = *(const float4*)(z + (size_t)(n0+node)*IND + ii);
        zl[ii+0][node] = zv.x; zl[ii+1][node] = zv.y; zl[ii+2][node] = zv.z; zl[ii+3][node] = zv.w;
    }
    __syncthreads();
    float aq[16], ak[16], av[16], ad[16];
    {
        float ba = bext[t], bb = bext[256+t], bc = bext[512+t], bd = bext[768+t];
        #pragma unroll
        for (int j = 0; j < 16; ++j) { aq[j]=ba; ak[j]=bb; av[j]=bc; ad[j]=bd; }
    }
    for (int i = 0; i < IND; ++i) {
        float wa = Wt[i*NCOL + t];
        float wb = Wt[i*NCOL + 256 + t];
        float wc = Wt[i*NCOL + 512 + t];
        float wd = Wt[i*NCOL + 768 + t];
        const float4* zr = (const float4*)(&zl[i][0]);
        float zz[16];
        #pragma unroll
        for (int c = 0; c < 4; ++c) {
            float4 zv = zr[c];
            zz[c*4+0]=zv.x; zz[c*4+1]=zv.y; zz[c*4+2]=zv.z; zz[c*4+3]=zv.w;
        }
        #pragma unroll
        for (int j = 0; j < 16; ++j) {
            aq[j] = fmaf(zz[j], wa, aq[j]);
            ak[j] = fmaf(zz[j], wb, ak[j]);
            av[j] = fmaf(zz[j], wc, av[j]);
            ad[j] = fmaf(zz[j], wd, ad[j]);
        }
    }
    int wv_ = t >> 6;
    #pragma unroll
    for (int j = 0; j < 16; ++j) {
        float sq = aq[j]*aq[j];
        float sk = ak[j]*ak[j];
        #pragma unroll
        for (int off = 32; off >= 1; off >>= 1) {
            sq += __shfl_xor(sq, off, 64);
            sk += __shfl_xor(sk, off, 64);
        }
        if ((t & 63) == 0) { diag[j][0][wv_] = 0.5f*sq; diag[j][1][wv_] = 0.5f*sk; }
    }
    #pragma unroll
    for (int j = 0; j < 16; ++j) vbuf[(size_t)(n0+j)*256 + t] = av[j];
    __syncthreads();
    if (t < 128) {
        int h = t >> 5, m = t & 31;
        bool valid = (m < M30);
        #pragma unroll
        for (int j = 0; j < 16; ++j) {
            float dq = ad[j];
            float mx = valid ? dq : -3.0e38f;
            #pragma unroll
            for (int off = 16; off >= 1; off >>= 1)
                mx = fmaxf(mx, __shfl_xor(mx, off, 32));
            float val = 0.f;
            if (valid) val = RATIO * (__expf(dq - diag[j][0][h] - mx) + EPSF);
            qp[(size_t)(n0+j)*128 + t] = val;
        }
    } else {
        int tt = t - 128;
        int h = tt >> 5, m = tt & 31;
        bool valid = (m < M30);
        float bm = -3.0e38f;
        #pragma unroll
        for (int j = 0; j < 16; ++j) {
            float dk = ad[j];
            kpb[(size_t)(n0+j)*128 + tt] = valid ? (dk - diag[j][1][h]) : 0.f;
            if (valid) bm = fmaxf(bm, dk);
        }
        #pragma unroll
        for (int off = 16; off >= 1; off >>= 1)
            bm = fmaxf(bm, __shfl_xor(bm, off, 32));
        if ((tt & 31) == 0) atomicMax(&stab[h], f2s(bm));
    }
}

__global__ void k_deg(const int* __restrict__ ei, int* __restrict__ din, int* __restrict__ dout) {
    int e = blockIdx.x*256 + threadIdx.x;
    if (e < EE) {
        atomicAdd(&dout[ei[e]], 1);
        atomicAdd(&din[ei[EE + e]], 1);
    }
}

// ---------- finish kp = ratio*(exp(dash-diag-stab)+eps) in place; accumulate kp_sum[h][m]
__global__ void k_kp(float* __restrict__ kpb, const unsigned* __restrict__ stab,
                     float* __restrict__ kp_sum) {
    __shared__ float red[256];
    int t = threadIdx.x;
    int hm = t & 127;
    int h = hm >> 5, m = hm & 31;
    float st = s2f(stab[h]);
    float ksum = 0.f;
    const int total = NN*128;
    for (int idx = blockIdx.x*256 + t; idx < total; idx += gridDim.x*256) {
        float val = kpb[idx];
        float kpv = 0.f;
        if (m < M30) kpv = RATIO * (__expf(val - st) + EPSF);
        kpb[idx] = kpv;
        ksum += kpv;
    }
    red[t] = ksum;
    __syncthreads();
    if (t < 128) atomicAdd(&kp_sum[hm], red[t] + red[t+128]);
}

// ---------- kvs[h][km][d] = sum_n (kp[n,m]*e^g[n,k]) * v[n,d]; ktg[h][km] = sum_n w
// block = (chunk of 512 nodes, head). 256 threads cover the 320x64 tile: 20 km x 4 d each.
__global__ __launch_bounds__(256) void k_kvs(const float* __restrict__ kpb, const float* __restrict__ g,
                      const float* __restrict__ vbuf,
                      float* __restrict__ kvs, float* __restrict__ ktg) {
    __shared__ float kp_l[8][32];
    __shared__ float eg_l[8][10];
    __shared__ float v_l[8][64];
    __shared__ float w_l[8][320];
    int t = threadIdx.x;
    int h = blockIdx.y;
    int n0 = blockIdx.x * 512;
    int gkm = t & 15, gd = t >> 4;
    int km0 = gkm * 20, d0 = gd * 4;
    float acc[20][4];
    float wsum[20];
    #pragma unroll
    for (int a = 0; a < 20; ++a) {
        wsum[a] = 0.f;
        #pragma unroll
        for (int b = 0; b < 4; ++b) acc[a][b] = 0.f;
    }
    for (int bt = 0; bt < 64; ++bt) {
        int nb0 = n0 + bt*8;
        __syncthreads();
        {
            int j = t >> 5, m = t & 31;
            int n = nb0 + j;
            kp_l[j][m] = (n < NN) ? kpb[(size_t)n*128 + h*32 + m] : 0.f;
        }
        if (t < 80) {
            int j = t / 10, k = t % 10;
            int n = nb0 + j;
            eg_l[j][k] = (n < NN) ? __expf(g[(size_t)n*40 + h*10 + k]) : 0.f;
        }
        #pragma unroll
        for (int ss = 0; ss < 2; ++ss) {
            int s = t + ss*256;
            int j = s >> 6, d = s & 63;
            int n = nb0 + j;
            v_l[j][d] = (n < NN) ? vbuf[(size_t)n*256 + h*64 + d] : 0.f;
        }
        __syncthreads();
        #pragma unroll
        for (int i = 0; i < 10; ++i) {
            int flat = i*256 + t;
            int j = flat / 320, km = flat % 320;
            w_l[j][km] = kp_l[j][km & 31] * eg_l[j][km >> 5];
        }
        __syncthreads();
        for (int j = 0; j < 8; ++j) {
            const float4* wp = (const float4*)(&w_l[j][km0]);
            float wv[20];
            #pragma unroll
            for (int c = 0; c < 5; ++c) {
                float4 w4 = wp[c];
                wv[c*4+0]=w4.x; wv[c*4+1]=w4.y; wv[c*4+2]=w4.z; wv[c*4+3]=w4.w;
            }
            float4 v4 = *(const float4*)(&v_l[j][d0]);
            float vv[4] = {v4.x, v4.y, v4.z, v4.w};
            #pragma unroll
            for (int a = 0; a < 20; ++a) {
                #pragma unroll
                for (int b = 0; b < 4; ++b)
                    acc[a][b] = fmaf(wv[a], vv[b], acc[a][b]);
            }
            if (gd == 0) {
                #pragma unroll
                for (int a = 0; a < 20; ++a) wsum[a] += wv[a];
            }
        }
    }
    float* kb = kvs + h*KM*64;
    #pragma unroll
    for (int a = 0; a < 20; ++a) {
        #pragma unroll
        for (int b = 0; b < 4; ++b)
            atomicAdd(&kb[(km0+a)*64 + d0 + b], acc[a][b]);
    }
    if (gd == 0) {
        #pragma unroll
        for (int a = 0; a < 20; ++a)
            atomicAdd(&ktg[h*KM + km0 + a], wsum[a]);
    }
}

// ---------- per node: norm/qpn (in place), z_den per k, z_next = mean_k(num/den)
__global__ __launch_bounds__(256) void k_znext(float* __restrict__ qp, const float* __restrict__ kvs,
                        const float* __restrict__ ktg, const float* __restrict__ kp_sum,
                        float* __restrict__ znext) {
    int t = threadIdx.x;
    int n = blockIdx.x*256 + t;
    int h = blockIdx.y;
    if (n >= NN) return;
    float q[32];
    float* qb = qp + (size_t)n*128 + h*32;
    #pragma unroll
    for (int c = 0; c < 8; ++c) {
        float4 v4 = *(const float4*)(qb + c*4);
        q[c*4+0]=v4.x; q[c*4+1]=v4.y; q[c*4+2]=v4.z; q[c*4+3]=v4.w;
    }
    const float* ks = kp_sum + h*32;
    float norm = 0.f;
    #pragma unroll
    for (int m = 0; m < 32; ++m) norm = fmaf(q[m], ks[m], norm);
    float rn = 1.f / norm;
    #pragma unroll
    for (int c = 0; c < 8; ++c) {
        float4 v4 = make_float4(q[c*4+0]*rn, q[c*4+1]*rn, q[c*4+2]*rn, q[c*4+3]*rn);
        *(float4*)(qb + c*4) = v4;
    }
    const float* kvh = kvs + h*KM*64;
    const float* kth = ktg + h*KM;
    float* zo = znext + (size_t)n*256 + h*64;
    for (int dc = 0; dc < 4; ++dc) {
        float ms[16];
        #pragma unroll
        for (int d = 0; d < 16; ++d) ms[d] = 0.f;
        for (int k = 0; k < 10; ++k) {
            float den = 0.f;
            #pragma unroll
            for (int m = 0; m < 32; ++m) den = fmaf(q[m], kth[k*32+m], den);
            float rd = 1.f / (den * 10.f);
            const float* base = kvh + k*2048 + dc*16;
            #pragma unroll
            for (int m = 0; m < 32; ++m) {
                float qm = q[m] * rd;
                #pragma unroll
                for (int d = 0; d < 16; ++d)
                    ms[d] = fmaf(qm, base[m*64 + d], ms[d]);
            }
        }
        #pragma unroll
        for (int d = 0; d < 16; ++d) zo[dc*16 + d] = ms[d];
    }
}

// ---------- A[e,h] = dot32(qpn[end], kp[start])
__global__ void k_edge(const int* __restrict__ ei, const float* __restrict__ qpn,
                       const float* __restrict__ kpb, float* __restrict__ A) {
    int gid = blockIdx.x*256 + threadIdx.x;
    int e = gid >> 2, h = gid & 3;
    int s = ei[e];
    int d = ei[EE + e];
    const float4* qr = (const float4*)(qpn + (size_t)d*128 + h*32);
    const float4* kr = (const float4*)(kpb + (size_t)s*128 + h*32);
    float acc = 0.f;
    #pragma unroll
    for (int c = 0; c < 8; ++c) {
        float4 a = qr[c], b = kr[c];
        acc += a.x*b.x + a.y*b.y + a.z*b.z + a.w*b.w;
    }
    A[gid] = acc;
}

// ---------- conv: znext[col] += sig_h * rsqrt(din[col]) * rsqrt(dout[row]) * v[row]
__global__ void k_conv(const int* __restrict__ ei, const int* __restrict__ din,
                       const int* __restrict__ dout, const float* __restrict__ vbuf,
                       const float* __restrict__ brb, float* __restrict__ znext) {
    int t = threadIdx.x;
    int e = blockIdx.x*4 + (t >> 6);
    int lane = t & 63;
    int row = ei[e];
    int col = ei[EE + e];
    float c = rsqrtf((float)din[col]) * rsqrtf((float)dout[row]);
    #pragma unroll
    for (int i = 0; i < 4; ++i) {
        float sig = 1.f / (1.f + __expf(-brb[i]));
        float val = sig * c * vbuf[(size_t)row*256 + i*64 + lane];
        atomicAdd(&znext[(size_t)col*256 + i*64 + lane], val);
    }
}

// ---------- out[n][o] = sum_f znext[n][f] * Wo[o][f] + Wob[o]
__global__ __launch_bounds__(256) void k_out(const float* __restrict__ znext, const float* __restrict__ WoT,
                      const float* __restrict__ Wob, float* __restrict__ out) {
    int n = blockIdx.x*256 + threadIdx.x;
    if (n >= NN) return;
    float acc[64];
    #pragma unroll
    for (int o = 0; o < 64; ++o) acc[o] = Wob[o];
    const float* zr = znext + (size_t)n*256;
    for (int fc = 0; fc < 64; ++fc) {
        float4 z4 = *(const float4*)(zr + fc*4);
        float zz[4] = {z4.x, z4.y, z4.z, z4.w};
        #pragma unroll
        for (int j = 0; j < 4; ++j) {
            const float* wr = WoT + (fc*4+j)*64;
            #pragma unroll
            for (int o = 0; o < 64; ++o)
                acc[o] = fmaf(zz[j], wr[o], acc[o]);
        }
    }
    float* ob = out + (size_t)n*64;
    #pragma unroll
    for (int o = 0; o < 64; ++o) ob[o] = acc[o];
}

extern "C" void kernel_launch(void* const* d_in, const int* in_sizes, int n_in,
                              void* d_out, int out_size, void* d_ws, size_t ws_size,
                              hipStream_t stream) {
    const float* z    = (const float*)d_in[0];
    const int*   ei   = (const int*)d_in[1];
    const float* Wq   = (const float*)d_in[2];
    const float* Wqb  = (const float*)d_in[3];
    const float* Wk   = (const float*)d_in[4];
    const float* Wkb  = (const float*)d_in[5];
    const float* Wv   = (const float*)d_in[6];
    const float* Wvb  = (const float*)d_in[7];
    const float* Wo   = (const float*)d_in[8];
    const float* Wob  = (const float*)d_in[9];
    const float* brb  = (const float*)d_in[10];
    const float* proj = (const float*)d_in[11];
    const float* g    = (const float*)d_in[12];
    float* out = (float*)d_out;
    float* A   = out + (size_t)NN*64;
    float* ws  = (float*)d_ws;

    float* Wt      = ws;                 // 131072
    float* bext    = ws + 131072;        // 1024
    float* WoT     = ws + 132096;        // 16384
    float* kvs     = ws + 148480;        // 81920
    float* ktg     = ws + 230400;        // 1280
    float* kp_sum  = ws + 231680;        // 128
    unsigned* stab = (unsigned*)(ws + 231808); // 4
    int* din       = (int*)(ws + 231812);      // 50000
    int* dout_     = (int*)(ws + 281812);      // 50000
    float* vbuf    = ws + 331840;        // 12.8M
    float* qp      = ws + 13131840;      // 6.4M
    float* kpb     = ws + 19531840;      // 6.4M
    float* znext   = ws + 25931840;      // 12.8M -> end 38731840 floats (~155 MB)

    hipMemsetAsync(ws + 148480, 0, (size_t)(331840 - 148480)*sizeof(float), stream);
    k_prep<<<128, 256, 0, stream>>>(Wq, Wqb, Wk, Wkb, Wv, Wvb, Wo, proj, Wt, bext, WoT);
    k_qkv<<<3125, 256, 0, stream>>>(z, Wt, bext, vbuf, qp, kpb, stab);
    k_deg<<<3125, 256, 0, stream>>>(ei, din, dout_);
    k_kp<<<512, 256, 0, stream>>>(kpb, stab, kp_sum);
    k_kvs<<<dim3(98,4), 256, 0, stream>>>(kpb, g, vbuf, kvs, ktg);
    k_znext<<<dim3(196,4), 256, 0, stream>>>(qp, kvs, ktg, kp_sum, znext);
    k_edge<<<12500, 256, 0, stream>>>(ei, qp, kpb, A);
    k_conv<<<200000, 256, 0, stream>>>(ei, din, dout_, vbuf, brb, znext);
    k_out<<<196, 256, 0, stream>>>(znext, WoT, Wob, out);
}

// Round 2
// 1359.347 us; speedup vs baseline: 1.3425x; 1.3425x over previous
//
#include <hip/hip_runtime.h>

#define NN 50000
#define EE 800000
#define IND 128
#define NCOL 1024
#define KM 320            // K * Mpad = 10*32
#define M30 30
#define RATIO 0.1825741858f   // 30^-0.5
#define EPSF 1e-6f
#define QKSCALE 0.7071067812f // (1/sqrt(0.25)) * 64^-0.25

__device__ __forceinline__ unsigned f2s(float f) {
    unsigned u = __float_as_uint(f);
    return (u & 0x80000000u) ? ~u : (u | 0x80000000u);
}
__device__ __forceinline__ float s2f(unsigned s) {
    return __uint_as_float((s & 0x80000000u) ? (s & 0x7fffffffu) : ~s);
}

// ---------- prep: Wt[IND][NCOL] (cols: 0-255 s*Wq^T, 256-511 s*Wk^T, 512-767 Wv^T,
// 768-895 Pq[h,m], 896-1023 Pk[h,m]), bias_ext[NCOL], WoT[256][64]
__global__ void k_prep(const float* __restrict__ Wq, const float* __restrict__ Wqb,
                       const float* __restrict__ Wk, const float* __restrict__ Wkb,
                       const float* __restrict__ Wv, const float* __restrict__ Wvb,
                       const float* __restrict__ Wo, const float* __restrict__ proj,
                       float* __restrict__ Wt, float* __restrict__ bext, float* __restrict__ WoT) {
    int i = blockIdx.x;   // 0..127
    int t = threadIdx.x;  // 0..255
    Wt[i*NCOL + t]       = QKSCALE * Wq[t*IND + i];
    Wt[i*NCOL + 256 + t] = QKSCALE * Wk[t*IND + i];
    Wt[i*NCOL + 512 + t] = Wv[t*IND + i];
    {
        const float* W = (t < 128) ? Wq : Wk;
        int c = (t < 128) ? t : (t - 128);
        int h = c >> 5, m = c & 31;
        float val = 0.f;
        if (m < M30) {
            for (int d = 0; d < 64; ++d)
                val += QKSCALE * W[(h*64+d)*IND + i] * proj[m*64 + d];
        }
        Wt[i*NCOL + 768 + t] = val;
    }
    if (t < 128) {
        int f = i*2 + (t >> 6);
        int o = t & 63;
        WoT[f*64 + o] = Wo[o*256 + f];
    }
    if (i == 0) {
        bext[t]       = QKSCALE * Wqb[t];
        bext[256 + t] = QKSCALE * Wkb[t];
        bext[512 + t] = Wvb[t];
        const float* Bb = (t < 128) ? Wqb : Wkb;
        int c = (t < 128) ? t : (t - 128);
        int h = c >> 5, m = c & 31;
        float val = 0.f;
        if (m < M30) {
            for (int d = 0; d < 64; ++d)
                val += QKSCALE * Bb[h*64+d] * proj[m*64 + d];
        }
        bext[768 + t] = val;
    }
}

// ---------- fused QKV + dash GEMM + feature maps. 16 nodes per block.
__global__ __launch_bounds__(256) void k_qkv(const float* __restrict__ z, const float* __restrict__ Wt,
                      const float* __restrict__ bext,
                      float* __restrict__ vbuf, float* __restrict__ qp, float* __restrict__ kpb,
                      unsigned* __restrict__ stab) {
    __shared__ float zl[IND][16];
    __shared__ float diag[16][2][4];
    int t = threadIdx.x;
    int n0 = blockIdx.x * 16;
    #pragma unroll
    for (int ss = 0; ss < 2; ++ss) {
        int s = t + ss*256;
        int node = s >> 5;
        int ii = (s & 31) * 4;
        float4 zv = *(const float4*)(z + (size_t)(n0+node)*IND + ii);
        zl[ii+0][node] = zv.x; zl[ii+1][node] = zv.y; zl[ii+2][node] = zv.z; zl[ii+3][node] = zv.w;
    }
    __syncthreads();
    float aq[16], ak[16], av[16], ad[16];
    {
        float ba = bext[t], bb = bext[256+t], bc = bext[512+t], bd = bext[768+t];
        #pragma unroll
        for (int j = 0; j < 16; ++j) { aq[j]=ba; ak[j]=bb; av[j]=bc; ad[j]=bd; }
    }
    for (int i = 0; i < IND; ++i) {
        float wa = Wt[i*NCOL + t];
        float wb = Wt[i*NCOL + 256 + t];
        float wc = Wt[i*NCOL + 512 + t];
        float wd = Wt[i*NCOL + 768 + t];
        const float4* zr = (const float4*)(&zl[i][0]);
        float zz[16];
        #pragma unroll
        for (int c = 0; c < 4; ++c) {
            float4 zv = zr[c];
            zz[c*4+0]=zv.x; zz[c*4+1]=zv.y; zz[c*4+2]=zv.z; zz[c*4+3]=zv.w;
        }
        #pragma unroll
        for (int j = 0; j < 16; ++j) {
            aq[j] = fmaf(zz[j], wa, aq[j]);
            ak[j] = fmaf(zz[j], wb, ak[j]);
            av[j] = fmaf(zz[j], wc, av[j]);
            ad[j] = fmaf(zz[j], wd, ad[j]);
        }
    }
    int wv_ = t >> 6;
    #pragma unroll
    for (int j = 0; j < 16; ++j) {
        float sq = aq[j]*aq[j];
        float sk = ak[j]*ak[j];
        #pragma unroll
        for (int off = 32; off >= 1; off >>= 1) {
            sq += __shfl_xor(sq, off, 64);
            sk += __shfl_xor(sk, off, 64);
        }
        if ((t & 63) == 0) { diag[j][0][wv_] = 0.5f*sq; diag[j][1][wv_] = 0.5f*sk; }
    }
    #pragma unroll
    for (int j = 0; j < 16; ++j) vbuf[(size_t)(n0+j)*256 + t] = av[j];
    __syncthreads();
    if (t < 128) {
        int h = t >> 5, m = t & 31;
        bool valid = (m < M30);
        #pragma unroll
        for (int j = 0; j < 16; ++j) {
            float dq = ad[j];
            float mx = valid ? dq : -3.0e38f;
            #pragma unroll
            for (int off = 16; off >= 1; off >>= 1)
                mx = fmaxf(mx, __shfl_xor(mx, off, 32));
            float val = 0.f;
            if (valid) val = RATIO * (__expf(dq - diag[j][0][h] - mx) + EPSF);
            qp[(size_t)(n0+j)*128 + t] = val;
        }
    } else {
        int tt = t - 128;
        int h = tt >> 5, m = tt & 31;
        bool valid = (m < M30);
        float bm = -3.0e38f;
        #pragma unroll
        for (int j = 0; j < 16; ++j) {
            float dk = ad[j];
            kpb[(size_t)(n0+j)*128 + tt] = valid ? (dk - diag[j][1][h]) : 0.f;
            if (valid) bm = fmaxf(bm, dk);
        }
        #pragma unroll
        for (int off = 16; off >= 1; off >>= 1)
            bm = fmaxf(bm, __shfl_xor(bm, off, 32));
        if ((tt & 31) == 0) atomicMax(&stab[h], f2s(bm));
    }
}

__global__ void k_deg(const int* __restrict__ ei, int* __restrict__ din, int* __restrict__ dout) {
    int e = blockIdx.x*256 + threadIdx.x;
    if (e < EE) {
        atomicAdd(&dout[ei[e]], 1);
        atomicAdd(&din[ei[EE + e]], 1);
    }
}

// rsdout[n] = dout>0 ? rsqrt(dout) : 0
__global__ void k_rs(const int* __restrict__ dout, float* __restrict__ rsd) {
    int i = blockIdx.x*256 + threadIdx.x;
    if (i < NN) {
        int d = dout[i];
        rsd[i] = d > 0 ? rsqrtf((float)d) : 0.f;
    }
}

// ---------- prefix sum over din (3-kernel scan) ----------
__global__ void k_scan_part(const int* __restrict__ din, int* __restrict__ bsum) {
    __shared__ int red[256];
    int t = threadIdx.x;
    int i = blockIdx.x*256 + t;
    red[t] = (i < NN) ? din[i] : 0;
    __syncthreads();
    for (int off = 128; off >= 1; off >>= 1) {
        if (t < off) red[t] += red[t+off];
        __syncthreads();
    }
    if (t == 0) bsum[blockIdx.x] = red[0];
}
__global__ void k_scan_top(const int* __restrict__ bsum, int* __restrict__ boff) {
    if (threadIdx.x == 0) {
        int acc = 0;
        for (int b = 0; b < 196; ++b) { boff[b] = acc; acc += bsum[b]; }
    }
}
__global__ void k_scan_fin(const int* __restrict__ din, const int* __restrict__ boff,
                           int* __restrict__ offsets, int* __restrict__ cursor) {
    __shared__ int s[256];
    int t = threadIdx.x;
    int i = blockIdx.x*256 + t;
    int v = (i < NN) ? din[i] : 0;
    s[t] = v;
    __syncthreads();
    for (int off = 1; off < 256; off <<= 1) {
        int add = (t >= off) ? s[t-off] : 0;
        __syncthreads();
        s[t] += add;
        __syncthreads();
    }
    int excl = s[t] - v + boff[blockIdx.x];
    if (i < NN) { offsets[i] = excl; cursor[i] = excl; }
    if (i == NN-1) offsets[NN] = excl + v;
}

// scatter edge rows into CSR-by-col order
__global__ void k_scatter(const int* __restrict__ ei, int* __restrict__ cursor,
                          int* __restrict__ csr_row) {
    int e = blockIdx.x*256 + threadIdx.x;
    if (e < EE) {
        int col = ei[EE + e];
        int pos = atomicAdd(&cursor[col], 1);
        csr_row[pos] = ei[e];
    }
}

// ---------- finish kp = ratio*(exp(dash-diag-stab)+eps) in place; accumulate kp_sum[h][m]
__global__ void k_kp(float* __restrict__ kpb, const unsigned* __restrict__ stab,
                     float* __restrict__ kp_sum) {
    __shared__ float red[256];
    int t = threadIdx.x;
    int hm = t & 127;
    int h = hm >> 5, m = hm & 31;
    float st = s2f(stab[h]);
    float ksum = 0.f;
    const int total = NN*128;
    for (int idx = blockIdx.x*256 + t; idx < total; idx += gridDim.x*256) {
        float val = kpb[idx];
        float kpv = 0.f;
        if (m < M30) kpv = RATIO * (__expf(val - st) + EPSF);
        kpb[idx] = kpv;
        ksum += kpv;
    }
    red[t] = ksum;
    __syncthreads();
    if (t < 128) atomicAdd(&kp_sum[hm], red[t] + red[t+128]);
}

// ---------- kvs[h][km][d] = sum_n (kp[n,m]*e^g[n,k]) * v[n,d]; ktg[h][km] = sum_n w
__global__ __launch_bounds__(256) void k_kvs(const float* __restrict__ kpb, const float* __restrict__ g,
                      const float* __restrict__ vbuf,
                      float* __restrict__ kvs, float* __restrict__ ktg) {
    __shared__ float kp_l[8][32];
    __shared__ float eg_l[8][10];
    __shared__ float v_l[8][64];
    __shared__ float w_l[8][320];
    int t = threadIdx.x;
    int h = blockIdx.y;
    int n0 = blockIdx.x * 512;
    int gkm = t & 15, gd = t >> 4;
    int km0 = gkm * 20, d0 = gd * 4;
    float acc[20][4];
    float wsum[20];
    #pragma unroll
    for (int a = 0; a < 20; ++a) {
        wsum[a] = 0.f;
        #pragma unroll
        for (int b = 0; b < 4; ++b) acc[a][b] = 0.f;
    }
    for (int bt = 0; bt < 64; ++bt) {
        int nb0 = n0 + bt*8;
        __syncthreads();
        {
            int j = t >> 5, m = t & 31;
            int n = nb0 + j;
            kp_l[j][m] = (n < NN) ? kpb[(size_t)n*128 + h*32 + m] : 0.f;
        }
        if (t < 80) {
            int j = t / 10, k = t % 10;
            int n = nb0 + j;
            eg_l[j][k] = (n < NN) ? __expf(g[(size_t)n*40 + h*10 + k]) : 0.f;
        }
        #pragma unroll
        for (int ss = 0; ss < 2; ++ss) {
            int s = t + ss*256;
            int j = s >> 6, d = s & 63;
            int n = nb0 + j;
            v_l[j][d] = (n < NN) ? vbuf[(size_t)n*256 + h*64 + d] : 0.f;
        }
        __syncthreads();
        #pragma unroll
        for (int i = 0; i < 10; ++i) {
            int flat = i*256 + t;
            int j = flat / 320, km = flat % 320;
            w_l[j][km] = kp_l[j][km & 31] * eg_l[j][km >> 5];
        }
        __syncthreads();
        for (int j = 0; j < 8; ++j) {
            const float4* wp = (const float4*)(&w_l[j][km0]);
            float wv[20];
            #pragma unroll
            for (int c = 0; c < 5; ++c) {
                float4 w4 = wp[c];
                wv[c*4+0]=w4.x; wv[c*4+1]=w4.y; wv[c*4+2]=w4.z; wv[c*4+3]=w4.w;
            }
            float4 v4 = *(const float4*)(&v_l[j][d0]);
            float vv[4] = {v4.x, v4.y, v4.z, v4.w};
            #pragma unroll
            for (int a = 0; a < 20; ++a) {
                #pragma unroll
                for (int b = 0; b < 4; ++b)
                    acc[a][b] = fmaf(wv[a], vv[b], acc[a][b]);
            }
            if (gd == 0) {
                #pragma unroll
                for (int a = 0; a < 20; ++a) wsum[a] += wv[a];
            }
        }
    }
    float* kb = kvs + h*KM*64;
    #pragma unroll
    for (int a = 0; a < 20; ++a) {
        #pragma unroll
        for (int b = 0; b < 4; ++b)
            atomicAdd(&kb[(km0+a)*64 + d0 + b], acc[a][b]);
    }
    if (gd == 0) {
        #pragma unroll
        for (int a = 0; a < 20; ++a)
            atomicAdd(&ktg[h*KM + km0 + a], wsum[a]);
    }
}

// ---------- per node: norm/qpn (in place), z_den per k, z_next = mean_k(num/den)
__global__ __launch_bounds__(256) void k_znext(float* __restrict__ qp, const float* __restrict__ kvs,
                        const float* __restrict__ ktg, const float* __restrict__ kp_sum,
                        float* __restrict__ znext) {
    int t = threadIdx.x;
    int n = blockIdx.x*256 + t;
    int h = blockIdx.y;
    if (n >= NN) return;
    float q[32];
    float* qb = qp + (size_t)n*128 + h*32;
    #pragma unroll
    for (int c = 0; c < 8; ++c) {
        float4 v4 = *(const float4*)(qb + c*4);
        q[c*4+0]=v4.x; q[c*4+1]=v4.y; q[c*4+2]=v4.z; q[c*4+3]=v4.w;
    }
    const float* ks = kp_sum + h*32;
    float norm = 0.f;
    #pragma unroll
    for (int m = 0; m < 32; ++m) norm = fmaf(q[m], ks[m], norm);
    float rn = 1.f / norm;
    #pragma unroll
    for (int c = 0; c < 8; ++c) {
        float4 v4 = make_float4(q[c*4+0]*rn, q[c*4+1]*rn, q[c*4+2]*rn, q[c*4+3]*rn);
        *(float4*)(qb + c*4) = v4;
    }
    const float* kvh = kvs + h*KM*64;
    const float* kth = ktg + h*KM;
    float* zo = znext + (size_t)n*256 + h*64;
    for (int dc = 0; dc < 4; ++dc) {
        float ms[16];
        #pragma unroll
        for (int d = 0; d < 16; ++d) ms[d] = 0.f;
        for (int k = 0; k < 10; ++k) {
            float den = 0.f;
            #pragma unroll
            for (int m = 0; m < 32; ++m) den = fmaf(q[m], kth[k*32+m], den);
            float rd = 1.f / (den * 10.f);
            const float* base = kvh + k*2048 + dc*16;
            #pragma unroll
            for (int m = 0; m < 32; ++m) {
                float qm = q[m] * rd;
                #pragma unroll
                for (int d = 0; d < 16; ++d)
                    ms[d] = fmaf(qm, base[m*64 + d], ms[d]);
            }
        }
        #pragma unroll
        for (int d = 0; d < 16; ++d) zo[dc*16 + d] = ms[d];
    }
}

// ---------- A[e,h] = dot32(qpn[end], kp[start])
__global__ void k_edge(const int* __restrict__ ei, const float* __restrict__ qpn,
                       const float* __restrict__ kpb, float* __restrict__ A) {
    int gid = blockIdx.x*256 + threadIdx.x;
    int e = gid >> 2, h = gid & 3;
    int s = ei[e];
    int d = ei[EE + e];
    const float4* qr = (const float4*)(qpn + (size_t)d*128 + h*32);
    const float4* kr = (const float4*)(kpb + (size_t)s*128 + h*32);
    float acc = 0.f;
    #pragma unroll
    for (int c = 0; c < 8; ++c) {
        float4 a = qr[c], b = kr[c];
        acc += a.x*b.x + a.y*b.y + a.z*b.z + a.w*b.w;
    }
    A[gid] = acc;
}

// ---------- conv (CSR gather): znext[col] += sig_h*rsqrt(din[col]) * sum_e rsdout[row]*v[row]
__global__ __launch_bounds__(256) void k_conv_csr(const int* __restrict__ offsets,
                        const int* __restrict__ csr_row, const int* __restrict__ din,
                        const float* __restrict__ rsd, const float* __restrict__ vbuf,
                        const float* __restrict__ brb, float* __restrict__ znext) {
    int t = threadIdx.x;
    int w = t >> 6, lane = t & 63;
    int col = blockIdx.x*4 + w;
    if (col >= NN) return;
    int s0 = offsets[col], s1 = offsets[col+1];
    if (s0 == s1) return;
    float4 acc = make_float4(0.f, 0.f, 0.f, 0.f);
    for (int j = s0; j < s1; ++j) {
        int row = csr_row[j];
        float rs = rsd[row];
        float4 u = *(const float4*)(vbuf + (size_t)row*256 + lane*4);
        acc.x = fmaf(rs, u.x, acc.x);
        acc.y = fmaf(rs, u.y, acc.y);
        acc.z = fmaf(rs, u.z, acc.z);
        acc.w = fmaf(rs, u.w, acc.w);
    }
    int h = lane >> 4;
    float sig = 1.f / (1.f + __expf(-brb[h]));
    float sc = sig * rsqrtf((float)din[col]);
    float* zp = znext + (size_t)col*256 + lane*4;
    float4 zv = *(float4*)zp;
    zv.x += sc*acc.x; zv.y += sc*acc.y; zv.z += sc*acc.z; zv.w += sc*acc.w;
    *(float4*)zp = zv;
}

// ---------- out[n][o] = sum_f znext[n][f] * Wo[o][f] + Wob[o]
__global__ __launch_bounds__(256) void k_out(const float* __restrict__ znext, const float* __restrict__ WoT,
                      const float* __restrict__ Wob, float* __restrict__ out) {
    int n = blockIdx.x*256 + threadIdx.x;
    if (n >= NN) return;
    float acc[64];
    #pragma unroll
    for (int o = 0; o < 64; ++o) acc[o] = Wob[o];
    const float* zr = znext + (size_t)n*256;
    for (int fc = 0; fc < 64; ++fc) {
        float4 z4 = *(const float4*)(zr + fc*4);
        float zz[4] = {z4.x, z4.y, z4.z, z4.w};
        #pragma unroll
        for (int j = 0; j < 4; ++j) {
            const float* wr = WoT + (fc*4+j)*64;
            #pragma unroll
            for (int o = 0; o < 64; ++o)
                acc[o] = fmaf(zz[j], wr[o], acc[o]);
        }
    }
    float* ob = out + (size_t)n*64;
    #pragma unroll
    for (int o = 0; o < 64; ++o) ob[o] = acc[o];
}

extern "C" void kernel_launch(void* const* d_in, const int* in_sizes, int n_in,
                              void* d_out, int out_size, void* d_ws, size_t ws_size,
                              hipStream_t stream) {
    const float* z    = (const float*)d_in[0];
    const int*   ei   = (const int*)d_in[1];
    const float* Wq   = (const float*)d_in[2];
    const float* Wqb  = (const float*)d_in[3];
    const float* Wk   = (const float*)d_in[4];
    const float* Wkb  = (const float*)d_in[5];
    const float* Wv   = (const float*)d_in[6];
    const float* Wvb  = (const float*)d_in[7];
    const float* Wo   = (const float*)d_in[8];
    const float* Wob  = (const float*)d_in[9];
    const float* brb  = (const float*)d_in[10];
    const float* proj = (const float*)d_in[11];
    const float* g    = (const float*)d_in[12];
    float* out = (float*)d_out;
    float* A   = out + (size_t)NN*64;
    float* ws  = (float*)d_ws;

    float* Wt      = ws;                 // 131072
    float* bext    = ws + 131072;        // 1024
    float* WoT     = ws + 132096;        // 16384
    float* kvs     = ws + 148480;        // 81920
    float* ktg     = ws + 230400;        // 1280
    float* kp_sum  = ws + 231680;        // 128
    unsigned* stab = (unsigned*)(ws + 231808); // 4
    int* din       = (int*)(ws + 231812);      // 50000
    int* dout_     = (int*)(ws + 281812);      // 50000
    float* vbuf    = ws + 331840;        // 12.8M
    float* qp      = ws + 13131840;      // 6.4M
    float* kpb     = ws + 19531840;      // 6.4M
    float* znext   = ws + 25931840;      // 12.8M
    // small scan scratch after znext (~0.6 MB)
    int* offsets   = (int*)(ws + 38731840);    // 50001 (pad to 50004)
    int* cursor    = (int*)(ws + 38781844);    // 50000
    int* bsum      = (int*)(ws + 38831844);    // 196
    int* boff      = (int*)(ws + 38832040);    // 196
    float* rsd     = ws + 38832236;            // 50000 -> end 38882236 floats (~155.5 MB)
    // csr_row (800000 ints) aliases qp, which is dead after k_edge
    int* csr_row   = (int*)qp;

    hipMemsetAsync(ws + 148480, 0, (size_t)(331840 - 148480)*sizeof(float), stream);
    k_prep<<<128, 256, 0, stream>>>(Wq, Wqb, Wk, Wkb, Wv, Wvb, Wo, proj, Wt, bext, WoT);
    k_qkv<<<3125, 256, 0, stream>>>(z, Wt, bext, vbuf, qp, kpb, stab);
    k_deg<<<3125, 256, 0, stream>>>(ei, din, dout_);
    k_rs<<<196, 256, 0, stream>>>(dout_, rsd);
    k_scan_part<<<196, 256, 0, stream>>>(din, bsum);
    k_scan_top<<<1, 64, 0, stream>>>(bsum, boff);
    k_scan_fin<<<196, 256, 0, stream>>>(din, boff, offsets, cursor);
    k_kp<<<512, 256, 0, stream>>>(kpb, stab, kp_sum);
    k_kvs<<<dim3(98,4), 256, 0, stream>>>(kpb, g, vbuf, kvs, ktg);
    k_znext<<<dim3(196,4), 256, 0, stream>>>(qp, kvs, ktg, kp_sum, znext);
    k_edge<<<12500, 256, 0, stream>>>(ei, qp, kpb, A);
    k_scatter<<<3125, 256, 0, stream>>>(ei, cursor, csr_row);   // csr_row aliases qp (dead now)
    k_conv_csr<<<12500, 256, 0, stream>>>(offsets, csr_row, din, rsd, vbuf, brb, znext);
    k_out<<<196, 256, 0, stream>>>(znext, WoT, Wob, out);
}